// Round 9
// baseline (351.693 us; speedup 1.0000x reference)
//
#include <hip/hip_runtime.h>

#define N 4096
#define IN_F 256
#define OUT_F 64
#define HEADS 4
#define ALPHA 0.2f
#define SEG 64    // max hits per quarter-row segment (mean ~5.1; >25 sigma margin)

typedef __attribute__((ext_vector_type(8))) short short8;
typedef __attribute__((ext_vector_type(4))) float f32x4;

__device__ __forceinline__ unsigned short f2bf(float f) {
    unsigned u = __builtin_bit_cast(unsigned, f);
    u += 0x7fffu + ((u >> 16) & 1u);            // round-to-nearest-even
    return (unsigned short)(u >> 16);
}

__device__ __forceinline__ float bf2f(unsigned short u) {
    return __builtin_bit_cast(float, (unsigned)u << 16);
}

// ---------------------------------------------------------------------------
// K1: cast x -> bf16 AND build transposed bf16 hamilton hamT[hd][f][k].
// ---------------------------------------------------------------------------
__global__ __launch_bounds__(256) void k_prep(const float* __restrict__ x,
                                              const float* __restrict__ W,
                                              unsigned short* __restrict__ xb,
                                              unsigned short* __restrict__ hamT) {
    const int tid = blockIdx.x * 256 + threadIdx.x;      // 262144 threads
    const float4 xv = *reinterpret_cast<const float4*>(x + (size_t)tid * 4);
    ushort4 o;
    o.x = f2bf(xv.x); o.y = f2bf(xv.y); o.z = f2bf(xv.z); o.w = f2bf(xv.w);
    *reinterpret_cast<ushort4*>(xb + (size_t)tid * 4) = o;

    if (tid < HEADS * OUT_F * IN_F) {                    // 65536
        const int hd = tid >> 14, f = (tid >> 8) & 63, k = tid & 255;
        const int q = k >> 6, kr = k & 63, p = f >> 4, fr = f & 15;
        const int   comp_t[4][4] = {{0,1,2,3},{1,0,3,2},{2,3,0,1},{3,2,1,0}};
        const float sign_t[4][4] = {{1.f,-1.f,-1.f,-1.f},
                                    {1.f, 1.f,-1.f, 1.f},
                                    {1.f, 1.f, 1.f,-1.f},
                                    {1.f,-1.f, 1.f, 1.f}};
        hamT[tid] = f2bf(sign_t[q][p] * W[(hd * 64 + kr) * 64 + comp_t[q][p] * 16 + fr]);
    }
}

// ---------------------------------------------------------------------------
// K2 body (shared by real + amp): h = x @ ham via bf16 MFMA.
// ---------------------------------------------------------------------------
__device__ __forceinline__ void h_body(const unsigned short* __restrict__ xb,
                                       const unsigned short* __restrict__ hamT,
                                       const float* __restrict__ a,
                                       unsigned short* __restrict__ hb,
                                       float* __restrict__ esp,
                                       float* __restrict__ edp,
                                       int gw, int lane) {
    const int rg = gw >> 3;
    const int hd = (gw >> 1) & 3;
    const int cf = gw & 1;
    const int m0 = rg * 16;
    const int r16 = lane & 15, g = lane >> 4;

    const unsigned short* xrow = xb + (size_t)(m0 + r16) * IN_F + g * 8;
    short8 af[8];
#pragma unroll
    for (int kk = 0; kk < 8; ++kk)
        af[kk] = *reinterpret_cast<const short8*>(xrow + kk * 32);

    f32x4 acc[2];
#pragma unroll
    for (int t = 0; t < 2; ++t) acc[t] = (f32x4){0.f, 0.f, 0.f, 0.f};

    const unsigned short* hbase = hamT + (size_t)(hd * 64 + cf * 32 + r16) * IN_F + g * 8;
#pragma unroll
    for (int kk = 0; kk < 8; ++kk) {
#pragma unroll
        for (int t = 0; t < 2; ++t) {
            const short8 bf = *reinterpret_cast<const short8*>(hbase + t * 16 * IN_F + kk * 32);
            acc[t] = __builtin_amdgcn_mfma_f32_16x16x32_bf16(af[kk], bf, acc[t], 0, 0, 0);
        }
    }

    float p[4] = {0.f, 0.f, 0.f, 0.f}, q[4] = {0.f, 0.f, 0.f, 0.f};
#pragma unroll
    for (int t = 0; t < 2; ++t) {
        const int fcol = cf * 32 + t * 16 + r16;
        const float as = a[hd * 128 + fcol];
        const float ad = a[hd * 128 + 64 + fcol];
#pragma unroll
        for (int j = 0; j < 4; ++j) {
            const float v = acc[t][j];
            hb[(size_t)(m0 + g * 4 + j) * (HEADS * OUT_F) + hd * 64 + fcol] = f2bf(v);
            p[j] = fmaf(v, as, p[j]);
            q[j] = fmaf(v, ad, q[j]);
        }
    }
#pragma unroll
    for (int off = 1; off < 16; off <<= 1) {
#pragma unroll
        for (int j = 0; j < 4; ++j) {
            p[j] += __shfl_xor(p[j], off);
            q[j] += __shfl_xor(q[j], off);
        }
    }
    if (r16 == 0) {
#pragma unroll
        for (int j = 0; j < 4; ++j) {
            const int row = m0 + g * 4 + j;
            esp[row * 8 + hd * 2 + cf] = p[j];
            edp[row * 8 + hd * 2 + cf] = q[j];
        }
    }
}

__global__ __launch_bounds__(256) void k_h(const unsigned short* __restrict__ xb,
                                           const unsigned short* __restrict__ hamT,
                                           const float* __restrict__ a,
                                           unsigned short* __restrict__ hb,
                                           float* __restrict__ esp,
                                           float* __restrict__ edp) {
    h_body(xb, hamT, a, hb, esp, edp, blockIdx.x * 4 + (threadIdx.x >> 6), threadIdx.x & 63);
}

// shadow: k_h work x32 into scratch (same addresses each rep; memory clobber
// prevents loop collapsing). Duration ~= 32 * t_h.
__global__ __launch_bounds__(256) void k_h_amp(const unsigned short* __restrict__ xb,
                                               const unsigned short* __restrict__ hamT,
                                               const float* __restrict__ a,
                                               unsigned short* __restrict__ hb2,
                                               float* __restrict__ esp2,
                                               float* __restrict__ edp2) {
    for (int rep = 0; rep < 32; ++rep) {
        asm volatile("" ::: "memory");
        h_body(xb, hamT, a, hb2, esp2, edp2, blockIdx.x * 4 + (threadIdx.x >> 6), threadIdx.x & 63);
    }
}

// ---------------------------------------------------------------------------
// K3 attention body. SCAN_ONLY=1: phase 1 + merge only (sunk to scr).
// ---------------------------------------------------------------------------
template <int SCAN_ONLY>
__device__ __forceinline__ void attn_body(const float* __restrict__ adj,
                                          const unsigned short* __restrict__ hb,
                                          const float* __restrict__ esp,
                                          const float* __restrict__ edp,
                                          float* __restrict__ out,
                                          int* __restrict__ scr,
                                          int i, int rep,
                                          int (*s_seg)[SEG], int* s_cnt,
                                          int* s_all, float (*s_z)[4 * SEG]) {
    const int wave = threadIdx.x >> 6;
    const int lane = threadIdx.x & 63;

    const uint4* arow = reinterpret_cast<const uint4*>(adj + (size_t)i * N) + wave * 256;
    uint4 av[4];
#pragma unroll
    for (int c = 0; c < 4; ++c) av[c] = arow[c * 64 + lane];

    const unsigned long long lmask_lt = (lane == 63) ? ~0ull >> 1
                                                     : (1ull << lane) - 1ull;
    int base = 0;
#pragma unroll
    for (int c = 0; c < 4; ++c) {
#pragma unroll
        for (int s = 0; s < 4; ++s) {
            const unsigned v = (s == 0) ? av[c].x : (s == 1) ? av[c].y
                             : (s == 2) ? av[c].z : av[c].w;
            const bool hit = v != 0u;
            const unsigned long long mk = __ballot(hit);
            if (hit) {
                const int pos = base + __popcll(mk & lmask_lt);
                if (pos < SEG)
                    s_seg[wave][pos] = wave * 1024 + c * 256 + lane * 4 + s;
            }
            base += __popcll(mk);
        }
    }
    if (lane == 0) s_cnt[wave] = base < SEG ? base : SEG;
    __syncthreads();

    const int c0 = s_cnt[0], c1 = s_cnt[1], c2 = s_cnt[2], c3 = s_cnt[3];
    const int wbase = (wave > 0 ? c0 : 0) + (wave > 1 ? c1 : 0) + (wave > 2 ? c2 : 0);
    const int wcnt = s_cnt[wave];
    if (lane < wcnt) s_all[wbase + lane] = s_seg[wave][lane];
    __syncthreads();
    const int cnt = c0 + c1 + c2 + c3;

    if (SCAN_ONLY) {
        if (threadIdx.x == 0) scr[rep * N + i] = cnt * 65536 + s_all[0];
        __syncthreads();
        return;
    }

    const int hd = wave;
    const float es = esp[i * 8 + hd * 2] + esp[i * 8 + hd * 2 + 1];
    float mh = -3.0e38f;
    for (int e = lane; e < cnt; e += 64) {
        const int j = s_all[e];
        const float ed = edp[j * 8 + hd * 2] + edp[j * 8 + hd * 2 + 1];
        float z = es + ed;
        z = z > 0.f ? z : ALPHA * z;
        s_z[hd][e] = z;
        mh = fmaxf(mh, z);
    }
#pragma unroll
    for (int off = 32; off > 0; off >>= 1) mh = fmaxf(mh, __shfl_xor(mh, off));

    float lsum = 0.f, acc = 0.f;
    int e = 0;
    for (; e + 4 <= cnt; e += 4) {
        const int j0 = s_all[e], j1 = s_all[e + 1], j2 = s_all[e + 2], j3 = s_all[e + 3];
        const unsigned short u0 = hb[(size_t)j0 * 256 + threadIdx.x];
        const unsigned short u1 = hb[(size_t)j1 * 256 + threadIdx.x];
        const unsigned short u2 = hb[(size_t)j2 * 256 + threadIdx.x];
        const unsigned short u3 = hb[(size_t)j3 * 256 + threadIdx.x];
        const float w0 = __expf(s_z[hd][e]     - mh);
        const float w1 = __expf(s_z[hd][e + 1] - mh);
        const float w2 = __expf(s_z[hd][e + 2] - mh);
        const float w3 = __expf(s_z[hd][e + 3] - mh);
        lsum += w0 + w1 + w2 + w3;
        acc = fmaf(w0, bf2f(u0), acc);
        acc = fmaf(w1, bf2f(u1), acc);
        acc = fmaf(w2, bf2f(u2), acc);
        acc = fmaf(w3, bf2f(u3), acc);
    }
    for (; e < cnt; ++e) {
        const int j = s_all[e];
        const unsigned short u = hb[(size_t)j * 256 + threadIdx.x];
        const float w = __expf(s_z[hd][e] - mh);
        lsum += w;
        acc = fmaf(w, bf2f(u), acc);
    }

    const float v = acc / lsum;
    out[(size_t)i * 256 + threadIdx.x] = v > 0.f ? v : __expf(v) - 1.f;
    __syncthreads();
}

__global__ __launch_bounds__(256) void k_attn(const float* __restrict__ adj,
                                              const unsigned short* __restrict__ hb,
                                              const float* __restrict__ esp,
                                              const float* __restrict__ edp,
                                              float* __restrict__ out) {
    __shared__ int   s_seg[4][SEG];
    __shared__ int   s_cnt[4];
    __shared__ int   s_all[4 * SEG];
    __shared__ float s_z[4][4 * SEG];
    attn_body<0>(adj, hb, esp, edp, out, nullptr, blockIdx.x, 0,
                 s_seg, s_cnt, s_all, s_z);
}

// shadow: attention x8 over a row permutation covering all rows each rep
// (512 MB adj traffic -> steady-state HBM). Duration ~= 8 * t_attn.
template <int SCAN_ONLY>
__global__ __launch_bounds__(256) void k_attn_amp(const float* __restrict__ adj,
                                                  const unsigned short* __restrict__ hb,
                                                  const float* __restrict__ esp,
                                                  const float* __restrict__ edp,
                                                  float* __restrict__ out2,
                                                  int* __restrict__ scr) {
    __shared__ int   s_seg[4][SEG];
    __shared__ int   s_cnt[4];
    __shared__ int   s_all[4 * SEG];
    __shared__ float s_z[4][4 * SEG];
    for (int rep = 0; rep < 8; ++rep) {
        asm volatile("" ::: "memory");
        const int i = (blockIdx.x + rep * 512) & (N - 1);
        attn_body<SCAN_ONLY>(adj, hb, esp, edp, out2, scr, i, rep,
                             s_seg, s_cnt, s_all, s_z);
    }
}

// ---------------------------------------------------------------------------
extern "C" void kernel_launch(void* const* d_in, const int* in_sizes, int n_in,
                              void* d_out, int out_size, void* d_ws, size_t ws_size,
                              hipStream_t stream) {
    const float* x   = (const float*)d_in[0];
    const float* adj = (const float*)d_in[1];
    const float* W   = (const float*)d_in[2];
    const float* a   = (const float*)d_in[3];
    float* out = (float*)d_out;

    float* ws   = (float*)d_ws;
    float* esp  = ws;                          // 32768 floats
    float* edp  = esp + N * 8;                 // 32768
    unsigned short* hb   = (unsigned short*)(edp + N * 8);  // 4096*256 bf16
    unsigned short* xb   = hb + (size_t)N * 256;            // 1048576 bf16
    unsigned short* hamT = xb + (size_t)N * IN_F;           // 65536 bf16
    // amp scratch
    unsigned short* hb2  = hamT + (size_t)HEADS * OUT_F * IN_F;  // 2 MB
    float* esp2 = (float*)(hb2 + (size_t)N * 256);          // 128 KB
    float* edp2 = esp2 + N * 8;                             // 128 KB
    float* out2 = edp2 + N * 8;                             // 4 MB
    int*   scr  = (int*)(out2 + (size_t)N * 256);           // 8*4096 ints

    // real pipeline (identical to round 8)
    k_prep<<<1024, 256, 0, stream>>>(x, W, xb, hamT);
    k_h<<<512, 256, 0, stream>>>(xb, hamT, a, hb, esp, edp);
    k_attn<<<N, 256, 0, stream>>>(adj, hb, esp, edp, out);

    // diagnostic shadows (scratch only; do not touch `out`)
    k_h_amp<<<512, 256, 0, stream>>>(xb, hamT, a, hb2, esp2, edp2);
    k_attn_amp<1><<<N, 256, 0, stream>>>(adj, hb, esp, edp, out2, scr);
    k_attn_amp<0><<<N, 256, 0, stream>>>(adj, hb, esp, edp, out2, scr);
}

// Round 10
// 39.021 us; speedup vs baseline: 9.0129x; 9.0129x over previous
//
#include <hip/hip_runtime.h>

#define N 4096
#define IN_F 256
#define OUT_F 64
#define HEADS 4
#define ALPHA 0.2f
#define SEG 64    // max hits per quarter-row segment (mean ~5.1; >25 sigma margin)

typedef __attribute__((ext_vector_type(8))) short short8;
typedef __attribute__((ext_vector_type(4))) float f32x4;

__device__ __forceinline__ unsigned short f2bf(float f) {
    unsigned u = __builtin_bit_cast(unsigned, f);
    u += 0x7fffu + ((u >> 16) & 1u);            // round-to-nearest-even
    return (unsigned short)(u >> 16);
}

__device__ __forceinline__ float bf2f(unsigned short u) {
    return __builtin_bit_cast(float, (unsigned)u << 16);
}

// ---------------------------------------------------------------------------
// K1: h = x @ ham via bf16 MFMA, fully fused (no prep kernel, no hamT/xb).
// One wave = 16 rows x 16 cols (quarter-head): 4096 tasks, 1024 blocks,
// 4 blocks/CU = 16 waves/CU.
// A: cast fp32 x in-register (identical to old xb). B: built from W with the
// quaternion sign/comp indexing (identical to old hamT). e-dots written as
// per-quarter partials esp/edp[row][hd][cq].
// ---------------------------------------------------------------------------
__global__ __launch_bounds__(256, 4) void k_h(const float* __restrict__ x,
                                              const float* __restrict__ W,
                                              const float* __restrict__ a,
                                              unsigned short* __restrict__ hb,
                                              float* __restrict__ esp,
                                              float* __restrict__ edp) {
    const int wave = threadIdx.x >> 6, lane = threadIdx.x & 63;
    const int gw = blockIdx.x * 4 + wave;     // 0..4095
    const int rg = gw >> 4;                   // 16-row group (0..255)
    const int hd = (gw >> 2) & 3;
    const int cq = gw & 3;                    // 16-col quarter of the head
    const int m0 = rg * 16;
    const int r16 = lane & 15, g = lane >> 4;

    const int   comp_t[4][4] = {{0,1,2,3},{1,0,3,2},{2,3,0,1},{3,2,1,0}};
    const float sign_t[4][4] = {{1.f,-1.f,-1.f,-1.f},
                                {1.f, 1.f,-1.f, 1.f},
                                {1.f, 1.f, 1.f,-1.f},
                                {1.f,-1.f, 1.f, 1.f}};

    // A fragments: rows m0+r16, k-run = kk*32 + g*8 .. +8 (fp32 -> bf16)
    const float* xrow = x + (size_t)(m0 + r16) * IN_F + g * 8;
    short8 af[8];
#pragma unroll
    for (int kk = 0; kk < 8; ++kk) {
        const float4 u0 = *reinterpret_cast<const float4*>(xrow + kk * 32);
        const float4 u1 = *reinterpret_cast<const float4*>(xrow + kk * 32 + 4);
        short8 t;
        t[0] = (short)f2bf(u0.x); t[1] = (short)f2bf(u0.y);
        t[2] = (short)f2bf(u0.z); t[3] = (short)f2bf(u0.w);
        t[4] = (short)f2bf(u1.x); t[5] = (short)f2bf(u1.y);
        t[6] = (short)f2bf(u1.z); t[7] = (short)f2bf(u1.w);
        af[kk] = t;
    }

    // B fragments: col f = cq*16 + r16 (p == cq, fr == r16), k-run as above.
    // q = kk>>1 (uniform per fragment); kr = (kk&1)*32 + g*8 + j.
    short8 bfr[8];
#pragma unroll
    for (int kk = 0; kk < 8; ++kk) {
        const int q = kk >> 1;
        const int kr0 = (kk & 1) * 32 + g * 8;
        const float s = sign_t[q][cq];
        const int c = comp_t[q][cq];
        const float* wp = W + (size_t)(hd * 64 + kr0) * 64 + c * 16 + r16;
        short8 t;
#pragma unroll
        for (int j = 0; j < 8; ++j) t[j] = (short)f2bf(s * wp[j * 64]);
        bfr[kk] = t;
    }

    f32x4 acc = (f32x4){0.f, 0.f, 0.f, 0.f};
#pragma unroll
    for (int kk = 0; kk < 8; ++kk)
        acc = __builtin_amdgcn_mfma_f32_16x16x32_bf16(af[kk], bfr[kk], acc, 0, 0, 0);

    // D layout: acc[j] at (row = m0 + g*4 + j, col f = cq*16 + r16)
    const int f = cq * 16 + r16;
    const float as = a[hd * 128 + f];
    const float ad = a[hd * 128 + 64 + f];
    float p[4], q2[4];
#pragma unroll
    for (int j = 0; j < 4; ++j) {
        const float v = acc[j];
        hb[(size_t)(m0 + g * 4 + j) * (HEADS * OUT_F) + hd * 64 + f] = f2bf(v);
        p[j] = v * as;
        q2[j] = v * ad;
    }
#pragma unroll
    for (int off = 1; off < 16; off <<= 1) {
#pragma unroll
        for (int j = 0; j < 4; ++j) {
            p[j] += __shfl_xor(p[j], off);
            q2[j] += __shfl_xor(q2[j], off);
        }
    }
    if (r16 == 0) {
#pragma unroll
        for (int j = 0; j < 4; ++j) {
            const int row = m0 + g * 4 + j;
            esp[row * 16 + hd * 4 + cq] = p[j];
            edp[row * 16 + hd * 4 + cq] = q2[j];
        }
    }
}

// ---------------------------------------------------------------------------
// K2: fused masked-softmax attention. ONE BLOCK PER ROW. (round-8 body)
// Phase 1: per-wave quarter-row ballot compaction -> merged LDS edge list.
// Phase 1.5: wave == head; exact per-row masked max, z cached in LDS.
// Phase 2: thread = (head, feature); unroll-4 pipelined bf16 h gather.
// ---------------------------------------------------------------------------
__global__ __launch_bounds__(256) void k_attn(const float* __restrict__ adj,
                                              const unsigned short* __restrict__ hb,
                                              const float* __restrict__ esp,
                                              const float* __restrict__ edp,
                                              float* __restrict__ out) {
    __shared__ int   s_seg[4][SEG];
    __shared__ int   s_cnt[4];
    __shared__ int   s_all[4 * SEG];
    __shared__ float s_z[4][4 * SEG];

    const int wave = threadIdx.x >> 6;
    const int lane = threadIdx.x & 63;
    const int i = blockIdx.x;

    // ---- phase 1: per-wave quarter-row compaction ----
    const uint4* arow = reinterpret_cast<const uint4*>(adj + (size_t)i * N) + wave * 256;
    uint4 av[4];
#pragma unroll
    for (int c = 0; c < 4; ++c) av[c] = arow[c * 64 + lane];

    const unsigned long long lmask_lt = (lane == 63) ? ~0ull >> 1
                                                     : (1ull << lane) - 1ull;
    int base = 0;
#pragma unroll
    for (int c = 0; c < 4; ++c) {
#pragma unroll
        for (int s = 0; s < 4; ++s) {
            const unsigned v = (s == 0) ? av[c].x : (s == 1) ? av[c].y
                             : (s == 2) ? av[c].z : av[c].w;
            const bool hit = v != 0u;            // adj entries are exactly 0/1
            const unsigned long long mk = __ballot(hit);
            if (hit) {
                const int pos = base + __popcll(mk & lmask_lt);
                if (pos < SEG)
                    s_seg[wave][pos] = wave * 1024 + c * 256 + lane * 4 + s;
            }
            base += __popcll(mk);
        }
    }
    if (lane == 0) s_cnt[wave] = base < SEG ? base : SEG;
    __syncthreads();

    // merge segments into one contiguous list (deterministic order)
    const int c0 = s_cnt[0], c1 = s_cnt[1], c2 = s_cnt[2], c3 = s_cnt[3];
    const int wbase = (wave > 0 ? c0 : 0) + (wave > 1 ? c1 : 0) + (wave > 2 ? c2 : 0);
    const int wcnt = s_cnt[wave];
    if (lane < wcnt) s_all[wbase + lane] = s_seg[wave][lane];
    __syncthreads();
    const int cnt = c0 + c1 + c2 + c3;

    // ---- phase 1.5: exact per-row masked max (wave == head) ----
    const int hd = wave;
    const float4 es4 = *reinterpret_cast<const float4*>(&esp[i * 16 + hd * 4]);
    const float es = (es4.x + es4.y) + (es4.z + es4.w);
    float mh = -3.0e38f;
    for (int e = lane; e < cnt; e += 64) {
        const int j = s_all[e];
        const float4 ed4 = *reinterpret_cast<const float4*>(&edp[j * 16 + hd * 4]);
        const float ed = (ed4.x + ed4.y) + (ed4.z + ed4.w);
        float z = es + ed;
        z = z > 0.f ? z : ALPHA * z;
        s_z[hd][e] = z;
        mh = fmaxf(mh, z);
    }
#pragma unroll
    for (int off = 32; off > 0; off >>= 1) mh = fmaxf(mh, __shfl_xor(mh, off));

    // ---- phase 2: thread = (head, feature); bf16 h gather ----
    float lsum = 0.f, acc = 0.f;
    int e = 0;
    for (; e + 4 <= cnt; e += 4) {
        const int j0 = s_all[e], j1 = s_all[e + 1], j2 = s_all[e + 2], j3 = s_all[e + 3];
        const unsigned short u0 = hb[(size_t)j0 * 256 + threadIdx.x];
        const unsigned short u1 = hb[(size_t)j1 * 256 + threadIdx.x];
        const unsigned short u2 = hb[(size_t)j2 * 256 + threadIdx.x];
        const unsigned short u3 = hb[(size_t)j3 * 256 + threadIdx.x];
        const float w0 = __expf(s_z[hd][e]     - mh);
        const float w1 = __expf(s_z[hd][e + 1] - mh);
        const float w2 = __expf(s_z[hd][e + 2] - mh);
        const float w3 = __expf(s_z[hd][e + 3] - mh);
        lsum += w0 + w1 + w2 + w3;
        acc = fmaf(w0, bf2f(u0), acc);
        acc = fmaf(w1, bf2f(u1), acc);
        acc = fmaf(w2, bf2f(u2), acc);
        acc = fmaf(w3, bf2f(u3), acc);
    }
    for (; e < cnt; ++e) {
        const int j = s_all[e];
        const unsigned short u = hb[(size_t)j * 256 + threadIdx.x];
        const float w = __expf(s_z[hd][e] - mh);
        lsum += w;
        acc = fmaf(w, bf2f(u), acc);
    }

    const float v = acc / lsum;
    out[(size_t)i * 256 + threadIdx.x] = v > 0.f ? v : __expf(v) - 1.f;
}

// ---------------------------------------------------------------------------
extern "C" void kernel_launch(void* const* d_in, const int* in_sizes, int n_in,
                              void* d_out, int out_size, void* d_ws, size_t ws_size,
                              hipStream_t stream) {
    const float* x   = (const float*)d_in[0];
    const float* adj = (const float*)d_in[1];
    const float* W   = (const float*)d_in[2];
    const float* a   = (const float*)d_in[3];
    float* out = (float*)d_out;

    float* ws  = (float*)d_ws;
    float* esp = ws;                           // 4096*16 = 65536 floats
    float* edp = esp + N * 16;                 // 65536
    unsigned short* hb = (unsigned short*)(edp + N * 16);   // 4096*256 bf16

    k_h<<<1024, 256, 0, stream>>>(x, W, a, hb, esp, edp);
    k_attn<<<N, 256, 0, stream>>>(adj, hb, esp, edp, out);
}

// Round 11
// 38.342 us; speedup vs baseline: 9.1725x; 1.0177x over previous
//
#include <hip/hip_runtime.h>

#define N 4096
#define IN_F 256
#define OUT_F 64
#define HEADS 4
#define ALPHA 0.2f
#define SEG 64      // max hits per quarter-row segment (mean ~5.1; >25 sigma)
#define LSTRIDE 320 // ints per row in the edge-list buffer (1280B, 64B-aligned)

typedef __attribute__((ext_vector_type(8))) short short8;
typedef __attribute__((ext_vector_type(4))) float f32x4;

__device__ __forceinline__ unsigned short f2bf(float f) {
    unsigned u = __builtin_bit_cast(unsigned, f);
    u += 0x7fffu + ((u >> 16) & 1u);            // round-to-nearest-even
    return (unsigned short)(u >> 16);
}

__device__ __forceinline__ float bf2f(unsigned short u) {
    return __builtin_bit_cast(float, (unsigned)u << 16);
}

// ---------------------------------------------------------------------------
// K1: fused {adj scan -> edge lists} || {h = x @ ham via bf16 MFMA}.
// Block i: 4 waves ballot-compact quarter-rows of adj row i (HBM stream);
// wave (i&3) additionally computes GEMM task i (16 rows x 16 cols) whose
// latency hides under the grid-wide scan traffic.
// ---------------------------------------------------------------------------
__global__ __launch_bounds__(256) void k_main(const float* __restrict__ x,
                                              const float* __restrict__ adj,
                                              const float* __restrict__ W,
                                              const float* __restrict__ a,
                                              unsigned short* __restrict__ hb,
                                              float* __restrict__ esp,
                                              float* __restrict__ edp,
                                              int* __restrict__ lists) {
    __shared__ int s_seg[4][SEG];
    __shared__ int s_cnt[4];
    __shared__ int s_all[4 * SEG];

    const int wave = threadIdx.x >> 6, lane = threadIdx.x & 63;
    const int i = blockIdx.x;

    // ---- designated wave: GEMM task i (R10 k_h body, gw = i) ----
    if (wave == (i & 3)) {
        const int gw = i;
        const int rg = gw >> 4;
        const int hd = (gw >> 2) & 3;
        const int cq = gw & 3;
        const int m0 = rg * 16;
        const int r16 = lane & 15, g = lane >> 4;

        const int   comp_t[4][4] = {{0,1,2,3},{1,0,3,2},{2,3,0,1},{3,2,1,0}};
        const float sign_t[4][4] = {{1.f,-1.f,-1.f,-1.f},
                                    {1.f, 1.f,-1.f, 1.f},
                                    {1.f, 1.f, 1.f,-1.f},
                                    {1.f,-1.f, 1.f, 1.f}};

        const float* xrow = x + (size_t)(m0 + r16) * IN_F + g * 8;
        short8 af[8];
#pragma unroll
        for (int kk = 0; kk < 8; ++kk) {
            const float4 u0 = *reinterpret_cast<const float4*>(xrow + kk * 32);
            const float4 u1 = *reinterpret_cast<const float4*>(xrow + kk * 32 + 4);
            short8 t;
            t[0] = (short)f2bf(u0.x); t[1] = (short)f2bf(u0.y);
            t[2] = (short)f2bf(u0.z); t[3] = (short)f2bf(u0.w);
            t[4] = (short)f2bf(u1.x); t[5] = (short)f2bf(u1.y);
            t[6] = (short)f2bf(u1.z); t[7] = (short)f2bf(u1.w);
            af[kk] = t;
        }

        short8 bfr[8];
#pragma unroll
        for (int kk = 0; kk < 8; ++kk) {
            const int q = kk >> 1;
            const int kr0 = (kk & 1) * 32 + g * 8;
            const float s = sign_t[q][cq];
            const int c = comp_t[q][cq];
            const float* wp = W + (size_t)(hd * 64 + kr0) * 64 + c * 16 + r16;
            short8 t;
#pragma unroll
            for (int j = 0; j < 8; ++j) t[j] = (short)f2bf(s * wp[j * 64]);
            bfr[kk] = t;
        }

        f32x4 acc = (f32x4){0.f, 0.f, 0.f, 0.f};
#pragma unroll
        for (int kk = 0; kk < 8; ++kk)
            acc = __builtin_amdgcn_mfma_f32_16x16x32_bf16(af[kk], bfr[kk], acc, 0, 0, 0);

        const int f = cq * 16 + r16;
        const float as = a[hd * 128 + f];
        const float ad = a[hd * 128 + 64 + f];
        float p[4], q2[4];
#pragma unroll
        for (int j = 0; j < 4; ++j) {
            const float v = acc[j];
            hb[(size_t)(m0 + g * 4 + j) * (HEADS * OUT_F) + hd * 64 + f] = f2bf(v);
            p[j] = v * as;
            q2[j] = v * ad;
        }
#pragma unroll
        for (int off = 1; off < 16; off <<= 1) {
#pragma unroll
            for (int j = 0; j < 4; ++j) {
                p[j] += __shfl_xor(p[j], off);
                q2[j] += __shfl_xor(q2[j], off);
            }
        }
        if (r16 == 0) {
#pragma unroll
            for (int j = 0; j < 4; ++j) {
                const int row = m0 + g * 4 + j;
                esp[row * 16 + hd * 4 + cq] = p[j];
                edp[row * 16 + hd * 4 + cq] = q2[j];
            }
        }
    }

    // ---- all waves: scan quarter `wave` of adj row i ----
    const uint4* arow = reinterpret_cast<const uint4*>(adj + (size_t)i * N) + wave * 256;
    uint4 av[4];
#pragma unroll
    for (int c = 0; c < 4; ++c) av[c] = arow[c * 64 + lane];

    const unsigned long long lmask_lt = (lane == 63) ? ~0ull >> 1
                                                     : (1ull << lane) - 1ull;
    int base = 0;
#pragma unroll
    for (int c = 0; c < 4; ++c) {
#pragma unroll
        for (int s = 0; s < 4; ++s) {
            const unsigned v = (s == 0) ? av[c].x : (s == 1) ? av[c].y
                             : (s == 2) ? av[c].z : av[c].w;
            const bool hit = v != 0u;            // adj entries are exactly 0/1
            const unsigned long long mk = __ballot(hit);
            if (hit) {
                const int pos = base + __popcll(mk & lmask_lt);
                if (pos < SEG)
                    s_seg[wave][pos] = wave * 1024 + c * 256 + lane * 4 + s;
            }
            base += __popcll(mk);
        }
    }
    if (lane == 0) s_cnt[wave] = base < SEG ? base : SEG;
    __syncthreads();

    // merge segments (deterministic order) and spill to global
    const int c0 = s_cnt[0], c1 = s_cnt[1], c2 = s_cnt[2], c3 = s_cnt[3];
    const int wbase = (wave > 0 ? c0 : 0) + (wave > 1 ? c1 : 0) + (wave > 2 ? c2 : 0);
    const int wcnt = s_cnt[wave];
    if (lane < wcnt) s_all[wbase + lane] = s_seg[wave][lane];
    __syncthreads();
    const int cnt = c0 + c1 + c2 + c3;

    if (threadIdx.x == 0) lists[(size_t)i * LSTRIDE] = cnt;
    for (int t = threadIdx.x; t < cnt; t += 256)
        lists[(size_t)i * LSTRIDE + 1 + t] = s_all[t];
}

// ---------------------------------------------------------------------------
// K2: per-row softmax + gather from the precomputed edge list (R10 phases
// 1.5/2). All operands (hb 2MB, edp 256KB, lists ~1MB) L2/L3-warm.
// ---------------------------------------------------------------------------
__global__ __launch_bounds__(256) void k_out(const unsigned short* __restrict__ hb,
                                             const float* __restrict__ esp,
                                             const float* __restrict__ edp,
                                             const int* __restrict__ lists,
                                             float* __restrict__ out) {
    __shared__ int   s_all[4 * SEG];
    __shared__ float s_z[4][4 * SEG];

    const int wave = threadIdx.x >> 6;
    const int lane = threadIdx.x & 63;
    const int i = blockIdx.x;

    const int cnt = lists[(size_t)i * LSTRIDE];
    for (int t = threadIdx.x; t < cnt; t += 256)
        s_all[t] = lists[(size_t)i * LSTRIDE + 1 + t];
    __syncthreads();

    // ---- exact per-row masked max (wave == head), z cached in LDS ----
    const int hd = wave;
    const float4 es4 = *reinterpret_cast<const float4*>(&esp[i * 16 + hd * 4]);
    const float es = (es4.x + es4.y) + (es4.z + es4.w);
    float mh = -3.0e38f;
    for (int e = lane; e < cnt; e += 64) {
        const int j = s_all[e];
        const float4 ed4 = *reinterpret_cast<const float4*>(&edp[j * 16 + hd * 4]);
        const float ed = (ed4.x + ed4.y) + (ed4.z + ed4.w);
        float z = es + ed;
        z = z > 0.f ? z : ALPHA * z;
        s_z[hd][e] = z;
        mh = fmaxf(mh, z);
    }
#pragma unroll
    for (int off = 32; off > 0; off >>= 1) mh = fmaxf(mh, __shfl_xor(mh, off));

    // ---- thread = (head, feature): bf16 h gather ----
    float lsum = 0.f, acc = 0.f;
    int e = 0;
    for (; e + 4 <= cnt; e += 4) {
        const int j0 = s_all[e], j1 = s_all[e + 1], j2 = s_all[e + 2], j3 = s_all[e + 3];
        const unsigned short u0 = hb[(size_t)j0 * 256 + threadIdx.x];
        const unsigned short u1 = hb[(size_t)j1 * 256 + threadIdx.x];
        const unsigned short u2 = hb[(size_t)j2 * 256 + threadIdx.x];
        const unsigned short u3 = hb[(size_t)j3 * 256 + threadIdx.x];
        const float w0 = __expf(s_z[hd][e]     - mh);
        const float w1 = __expf(s_z[hd][e + 1] - mh);
        const float w2 = __expf(s_z[hd][e + 2] - mh);
        const float w3 = __expf(s_z[hd][e + 3] - mh);
        lsum += w0 + w1 + w2 + w3;
        acc = fmaf(w0, bf2f(u0), acc);
        acc = fmaf(w1, bf2f(u1), acc);
        acc = fmaf(w2, bf2f(u2), acc);
        acc = fmaf(w3, bf2f(u3), acc);
    }
    for (; e < cnt; ++e) {
        const int j = s_all[e];
        const unsigned short u = hb[(size_t)j * 256 + threadIdx.x];
        const float w = __expf(s_z[hd][e] - mh);
        lsum += w;
        acc = fmaf(w, bf2f(u), acc);
    }

    const float v = acc / lsum;
    out[(size_t)i * 256 + threadIdx.x] = v > 0.f ? v : __expf(v) - 1.f;
}

// ---------------------------------------------------------------------------
extern "C" void kernel_launch(void* const* d_in, const int* in_sizes, int n_in,
                              void* d_out, int out_size, void* d_ws, size_t ws_size,
                              hipStream_t stream) {
    const float* x   = (const float*)d_in[0];
    const float* adj = (const float*)d_in[1];
    const float* W   = (const float*)d_in[2];
    const float* a   = (const float*)d_in[3];
    float* out = (float*)d_out;

    float* ws  = (float*)d_ws;
    float* esp = ws;                                        // 4096*16 floats
    float* edp = esp + N * 16;                              // 4096*16
    unsigned short* hb = (unsigned short*)(edp + N * 16);   // 4096*256 bf16
    int* lists = (int*)(hb + (size_t)N * 256);              // 4096*320 ints

    k_main<<<N, 256, 0, stream>>>(x, adj, W, a, hb, esp, edp, lists);
    k_out<<<N, 256, 0, stream>>>(hb, esp, edp, lists, out);
}